// Round 1
// baseline (185.855 us; speedup 1.0000x reference)
//
#include <hip/hip_runtime.h>

// WaveletTransform: 2x2 Haar subbands (LL,LH,HL,HH) of x[8,64,256,256] f32,
// each bilinearly upsampled (jax.image.resize half-pixel semantics) back to
// 256x256. Fully fused: one thread = one 2x2 output block for all 4 subbands.
//
// jax.image.resize bilinear 128->256 weights (verified against
// compute_weight_mat): out[2k] = 0.25*S[k-1] + 0.75*S[k],
// out[2k+1] = 0.75*S[k] + 0.25*S[k+1], edges equivalent to clamped indexing.

#define IW 256
#define IH 256
#define SW 128
#define SH 128
#define NIMG 512   // 8*64

__global__ __launch_bounds__(256) void WaveletTransform_56075093016893_kernel(
    const float* __restrict__ x, float* __restrict__ out)
{
    const int tid = threadIdx.x;
    const int kx  = tid & 127;                         // subband col 0..127
    const int ky  = (blockIdx.x << 1) | (tid >> 7);    // subband row 0..127
    const int img = blockIdx.y;                        // 0..511 (= b*64+c)

    const float* __restrict__ xin = x + (size_t)img * (IH * IW);

    // 3x3 subband neighborhood, all 4 subbands, computed from 2x2 input blocks.
    float S[4][3][3];
    #pragma unroll
    for (int jr = 0; jr < 3; ++jr) {
        int kr = ky - 1 + jr;
        kr = kr < 0 ? 0 : (kr > SH - 1 ? SH - 1 : kr);
        const float* r0 = xin + (size_t)(2 * kr) * IW;
        const float* r1 = r0 + IW;
        #pragma unroll
        for (int jc = 0; jc < 3; ++jc) {
            int kc = kx - 1 + jc;
            kc = kc < 0 ? 0 : (kc > SW - 1 ? SW - 1 : kc);
            float2 t = *(const float2*)(r0 + 2 * kc);
            float2 u = *(const float2*)(r1 + 2 * kc);
            float a = t.x, b = t.y, c = u.x, d = u.y;
            float ab = a + b, cd = c + d, amb = a - b, cmd = c - d;
            S[0][jr][jc] = (ab + cd) * 0.5f;   // LL
            S[1][jr][jc] = (ab - cd) * 0.5f;   // LH
            S[2][jr][jc] = (amb + cmd) * 0.5f; // HL
            S[3][jr][jc] = (amb - cmd) * 0.5f; // HH
        }
    }

    const size_t plane   = (size_t)NIMG * IH * IW;    // elems per subband output
    const size_t imgoff  = (size_t)img * (IH * IW);
    const size_t rowtop  = (size_t)(2 * ky) * IW + 2 * kx;
    const size_t rowbot  = rowtop + IW;

    #pragma unroll
    for (int s = 0; s < 4; ++s) {
        // x-direction interp per support row
        float xl[3], xr[3];
        #pragma unroll
        for (int jr = 0; jr < 3; ++jr) {
            xl[jr] = 0.25f * S[s][jr][0] + 0.75f * S[s][jr][1];
            xr[jr] = 0.75f * S[s][jr][1] + 0.25f * S[s][jr][2];
        }
        // y-direction interp
        float2 top, bot;
        top.x = 0.25f * xl[0] + 0.75f * xl[1];
        top.y = 0.25f * xr[0] + 0.75f * xr[1];
        bot.x = 0.75f * xl[1] + 0.25f * xl[2];
        bot.y = 0.75f * xr[1] + 0.25f * xr[2];

        float* o = out + (size_t)s * plane + imgoff;
        *(float2*)(o + rowtop) = top;
        *(float2*)(o + rowbot) = bot;
    }
}

extern "C" void kernel_launch(void* const* d_in, const int* in_sizes, int n_in,
                              void* d_out, int out_size, void* d_ws, size_t ws_size,
                              hipStream_t stream) {
    const float* x = (const float*)d_in[0];
    float* out = (float*)d_out;
    // grid: 64 ky-pairs, 512 images; block: 256 threads (128 kx * 2 ky)
    dim3 grid(64, NIMG);
    dim3 block(256);
    WaveletTransform_56075093016893_kernel<<<grid, block, 0, stream>>>(x, out);
}

// Round 3
// 106.339 us; speedup vs baseline: 1.7478x; 1.7478x over previous
//
#include <hip/hip_runtime.h>

// WaveletTransform: 2x2 Haar subbands (LL,LH,HL,HH) of x[8,64,256,256] f32,
// each bilinearly upsampled (jax.image.resize half-pixel, verified) back to
// 256x256. Fused one-pass. Thread = 4x4 output tile per subband:
//   thread (kq, j) owns output rows 4kq..4kq+3, cols 4j..4j+3, all 4 subbands.
// Needs S (subband) support rows 2kq-1..2kq+2, cols 2j-1..2j+2 (clamped),
// i.e. input rows 4kq-2..4kq+5, cols 4j-2..4j+5 -> per row: float2+float4+float2.
//
// resize weights (128->256, half-pixel): out[2k]=0.25*S[k-1]+0.75*S[k],
// out[2k+1]=0.75*S[k]+0.25*S[k+1]; edges == clamped indexing (validated R1).

#define IW 256
#define NIMG 512   // 8*64

typedef float f32x4 __attribute__((ext_vector_type(4)));  // native vec for nontemporal store

__global__ __launch_bounds__(256) void WaveletTransform_56075093016893_kernel(
    const float* __restrict__ x, float* __restrict__ out)
{
    const int tid = threadIdx.x;
    const int j   = tid & 63;                        // S col-pair 0..63
    const int kq  = (blockIdx.x << 2) | (tid >> 6);  // S row-pair 0..63
    const int img = blockIdx.y;                      // 0..511

    const float* __restrict__ xin = x + (size_t)img * (IW * IW);

    // input col offsets (elements); all 8B/16B aligned
    const int col_lo  = (j == 0)  ? 0   : 4 * j - 2;  // float2 -> S col 2j-1 (clamped)
    const int col_mid = 4 * j;                        // float4 -> S cols 2j, 2j+1
    const int col_hi  = (j == 63) ? 254 : 4 * j + 4;  // float2 -> S col 2j+2 (clamped)

    float S[4][4][4];  // [subband][support row t][support col cc]

    #pragma unroll
    for (int t = 0; t < 4; ++t) {
        int r = 2 * kq - 1 + t;                       // S row, clamp to [0,127]
        r = r < 0 ? 0 : (r > 127 ? 127 : r);
        const float* r0 = xin + (size_t)(2 * r) * IW;
        const float* r1 = r0 + IW;
        float2 tl = *(const float2*)(r0 + col_lo);
        float4 tm = *(const float4*)(r0 + col_mid);
        float2 th = *(const float2*)(r0 + col_hi);
        float2 bl = *(const float2*)(r1 + col_lo);
        float4 bm = *(const float4*)(r1 + col_mid);
        float2 bh = *(const float2*)(r1 + col_hi);
        float ta[4] = {tl.x, tm.x, tm.z, th.x};
        float tb[4] = {tl.y, tm.y, tm.w, th.y};
        float ba[4] = {bl.x, bm.x, bm.z, bh.x};
        float bb[4] = {bl.y, bm.y, bm.w, bh.y};
        #pragma unroll
        for (int cc = 0; cc < 4; ++cc) {
            float ab  = ta[cc] + tb[cc], cd  = ba[cc] + bb[cc];
            float amb = ta[cc] - tb[cc], cmd = ba[cc] - bb[cc];
            S[0][t][cc] = (ab + cd) * 0.5f;   // LL
            S[1][t][cc] = (ab - cd) * 0.5f;   // LH
            S[2][t][cc] = (amb + cmd) * 0.5f; // HL
            S[3][t][cc] = (amb - cmd) * 0.5f; // HH
        }
    }

    const size_t plane = (size_t)NIMG * IW * IW;
    float* obase = out + (size_t)img * (IW * IW) + (size_t)(4 * kq) * IW + 4 * j;

    #pragma unroll
    for (int s = 0; s < 4; ++s) {
        float xv[4][4];  // x-interpolated, per support row
        #pragma unroll
        for (int t = 0; t < 4; ++t) {
            xv[t][0] = 0.25f * S[s][t][0] + 0.75f * S[s][t][1];
            xv[t][1] = 0.75f * S[s][t][1] + 0.25f * S[s][t][2];
            xv[t][2] = 0.25f * S[s][t][1] + 0.75f * S[s][t][2];
            xv[t][3] = 0.75f * S[s][t][2] + 0.25f * S[s][t][3];
        }
        float* o = obase + (size_t)s * plane;
        #pragma unroll
        for (int q = 0; q < 4; ++q) {
            const int   t0 = (q == 0) ? 0 : (q == 3) ? 2 : 1;
            const int   t1 = t0 + 1;
            const float w0 = (q == 0 || q == 2) ? 0.25f : 0.75f;
            const float w1 = 1.0f - w0;
            f32x4 v;
            v.x = w0 * xv[t0][0] + w1 * xv[t1][0];
            v.y = w0 * xv[t0][1] + w1 * xv[t1][1];
            v.z = w0 * xv[t0][2] + w1 * xv[t1][2];
            v.w = w0 * xv[t0][3] + w1 * xv[t1][3];
            __builtin_nontemporal_store(v, (f32x4*)(o + (size_t)q * IW));
        }
    }
}

extern "C" void kernel_launch(void* const* d_in, const int* in_sizes, int n_in,
                              void* d_out, int out_size, void* d_ws, size_t ws_size,
                              hipStream_t stream) {
    const float* x = (const float*)d_in[0];
    float* out = (float*)d_out;
    // grid: 16 row-quads (64 kq / 4 per block), 512 images; 256 threads
    dim3 grid(16, NIMG);
    dim3 block(256);
    WaveletTransform_56075093016893_kernel<<<grid, block, 0, stream>>>(x, out);
}